// Round 20
// baseline (208.669 us; speedup 1.0000x reference)
//
#include <hip/hip_runtime.h>
#include <cstdint>

// Problem constants (from reference)
constexpr int B_   = 4096;
constexpr int T_   = 512;
constexpr int DIN  = 10;
constexpr int H_   = 20;
constexpr int DOUT = 2;

typedef float    v2f __attribute__((ext_vector_type(2)));
typedef float    v4f __attribute__((ext_vector_type(4)));
typedef _Float16 v8h __attribute__((ext_vector_type(8)));
typedef __fp16   fp2t __attribute__((ext_vector_type(2)));

constexpr float SCL = 2.885390082f;   // 2*log2(e), folded into weights/biases

#define CFENCE() asm volatile("" ::: "memory")

// tanh from PRE-SCALED input s = 2*log2e*v: 4-op chain, exact saturation
__device__ __forceinline__ float tanh_pre(float s) {
    float e = __builtin_amdgcn_exp2f(s);
    float r = __builtin_amdgcn_rcpf(e + 1.0f);
    return fmaf(-2.0f, r, 1.0f);
}

union B8 { v8h v; fp2t p[4]; };   // B fragment as 4 packed f16x2

__device__ __forceinline__ v4f mfma16(v8h a, v8h b, v4f c) {
    return __builtin_amdgcn_mfma_f32_16x16x32_f16(a, b, c, 0, 0, 0);
}

// MFMA-RNN: wave = 16 samples; the matrix product IS the all-to-all
// (no LDS/DPP/bpermute on the recurrent chain -- R9-R19 showed any DS
// exchange costs a ~400cyc write->read turnaround per step).
//
// D layout (VERIFIED, docs m89): col = lane&15, row(within 16-tile) =
//   (lane>>4)*4 + reg.  A/B layout (standard CDNA4): A row m = lane&15,
//   k = 8*(lane>>4)+e; B col n = lane&15, k = 8*(lane>>4)+e (e=2p+half).
// Output-row permutation j(M,m) = 8*(m>>2) + 4*M + (m&3) makes lane
// (n,h) receive exactly state elements j = 8h..8h+7 across its two
// M-tiles -> D-to-B repack is PURE IN-LANE (4x cvt_pkrtz).
// Pad rows (j>=20): zero weights + zero bias -> tanh(0)=0 forever.
// Pad x-cols (k>=10): zero A columns kill garbage B values.
extern "C" __global__ void __launch_bounds__(64, 1)
rnn_mfma(const float* __restrict__ x,
         const float* __restrict__ w_ih0, const float* __restrict__ w_hh0,
         const float* __restrict__ b_ih0, const float* __restrict__ b_hh0,
         const float* __restrict__ w_ih1, const float* __restrict__ w_hh1,
         const float* __restrict__ b_ih1, const float* __restrict__ b_hh1,
         const float* __restrict__ fc_w, const float* __restrict__ fc_b,
         float* __restrict__ out)
{
    const int lane = threadIdx.x;
    const int n    = lane & 15;          // sample col (and A row m)
    const int hq   = lane >> 4;          // 0..3
    const int kb   = 8 * hq;             // k base of this lane's A/B frag
    const int samp = blockIdx.x * 16 + n;   // grid=256 -> always < B_

    __shared__ float ldsF[16][20];       // epilogue FC buffer

    // ---- A fragments (weights, pre-scaled, row-permuted), 2 M-tiles ----
    v8h wh0A[2], wx0A[2], wi1A[2], wh1A[2];
    v4f bias0c[2], bias1c[2];
    #pragma unroll
    for (int M = 0; M < 2; ++M) {
        const int m  = n;                          // this lane's A row
        const int j0 = 8 * (m >> 2) + 4 * M + (m & 3);   // permuted output row
        #pragma unroll
        for (int e = 0; e < 8; ++e) {
            const int k = kb + e;
            const bool jr = (j0 < H_);
            wh0A[M][e] = (_Float16)((jr && k < H_)  ? SCL * w_hh0[j0 * H_ + k]   : 0.f);
            wx0A[M][e] = (_Float16)((jr && k < DIN) ? SCL * w_ih0[j0 * DIN + k]  : 0.f);
            wi1A[M][e] = (_Float16)((jr && k < H_)  ? SCL * w_ih1[j0 * H_ + k]   : 0.f);
            wh1A[M][e] = (_Float16)((jr && k < H_)  ? SCL * w_hh1[j0 * H_ + k]   : 0.f);
        }
        // C-init biases in D layout: lane (n,hq) reg r -> j = 8*hq + 4*M + r
        #pragma unroll
        for (int r = 0; r < 4; ++r) {
            const int j = 8 * hq + 4 * M + r;
            bias0c[M][r] = (j < H_) ? SCL * (b_ih0[j] + b_hh0[j]) : 0.f;
            bias1c[M][r] = (j < H_) ? SCL * (b_ih1[j] + b_hh1[j]) : 0.f;
        }
    }

    // ---- state B fragments (zero-init = h1(-1)=h2(-1)=0) ----
    B8 h1B, h2B;
    #pragma unroll
    for (int p = 0; p < 4; ++p) {
        h1B.p[p] = __builtin_amdgcn_cvt_pkrtz(0.f, 0.f);
        h2B.p[p] = __builtin_amdgcn_cvt_pkrtz(0.f, 0.f);
    }

    // ---- x pipeline: lane (n,hq) supplies B_x k = kb..kb+7 ----
    // hq==0 -> x[0..7]; hq==1 -> x[8..9] (+garbage, killed by zero A cols);
    // hq>=2 -> all-garbage (killed). Offsets chosen to stay in-bounds.
    const float* xr = x + (size_t)samp * (T_ * DIN);
    int xo[4];
    if (hq == 0)      { xo[0] = 0; xo[1] = 2; xo[2] = 4; xo[3] = 6; }
    else if (hq == 1) { xo[0] = 8; xo[1] = 0; xo[2] = 2; xo[3] = 4; }
    else              { xo[0] = 0; xo[1] = 2; xo[2] = 4; xo[3] = 6; }

    v2f xraw[4];
    auto load_x = [&](int t) {
        const float* bt = xr + (size_t)t * DIN;
        #pragma unroll
        for (int p = 0; p < 4; ++p)
            xraw[p] = *reinterpret_cast<const v2f*>(bt + xo[p]);
    };
    load_x(0);

    float h2f0[4], h2f1[4];   // last L1 tanh outputs (f32) for epilogue

    for (int t = 0; t < T_; ++t) {
        // ---- pack x fragment, then prefetch next row ----
        B8 xB;
        #pragma unroll
        for (int p = 0; p < 4; ++p)
            xB.p[p] = __builtin_amdgcn_cvt_pkrtz(xraw[p].x, xraw[p].y);
        load_x((t + 1 < T_) ? (t + 1) : (T_ - 1));

        // ---- L0: h1(t) = tanh(bias0 + Wh0.h1(t-1) + Wih0.x(t)) ----
        v4f a0 = mfma16(wh0A[0], h1B.v, bias0c[0]);
        a0     = mfma16(wx0A[0], xB.v,  a0);
        v4f a1 = mfma16(wh0A[1], h1B.v, bias0c[1]);
        a1     = mfma16(wx0A[1], xB.v,  a1);
        float u00 = tanh_pre(a0[0]), u01 = tanh_pre(a0[1]);
        float u02 = tanh_pre(a0[2]), u03 = tanh_pre(a0[3]);
        float u10 = tanh_pre(a1[0]), u11 = tanh_pre(a1[1]);
        float u12 = tanh_pre(a1[2]), u13 = tanh_pre(a1[3]);
        B8 nh1;
        nh1.p[0] = __builtin_amdgcn_cvt_pkrtz(u00, u01);   // j = 8h+0,1
        nh1.p[1] = __builtin_amdgcn_cvt_pkrtz(u02, u03);   // j = 8h+2,3
        nh1.p[2] = __builtin_amdgcn_cvt_pkrtz(u10, u11);   // j = 8h+4,5
        nh1.p[3] = __builtin_amdgcn_cvt_pkrtz(u12, u13);   // j = 8h+6,7

        // ---- L1: h2(t) = tanh(bias1 + Wi1.h1(t) + Wh1.h2(t-1)) ----
        v4f c0 = mfma16(wi1A[0], nh1.v, bias1c[0]);
        c0     = mfma16(wh1A[0], h2B.v, c0);
        v4f c1 = mfma16(wi1A[1], nh1.v, bias1c[1]);
        c1     = mfma16(wh1A[1], h2B.v, c1);
        h2f0[0] = tanh_pre(c0[0]); h2f0[1] = tanh_pre(c0[1]);
        h2f0[2] = tanh_pre(c0[2]); h2f0[3] = tanh_pre(c0[3]);
        h2f1[0] = tanh_pre(c1[0]); h2f1[1] = tanh_pre(c1[1]);
        h2f1[2] = tanh_pre(c1[2]); h2f1[3] = tanh_pre(c1[3]);
        B8 nh2;
        nh2.p[0] = __builtin_amdgcn_cvt_pkrtz(h2f0[0], h2f0[1]);
        nh2.p[1] = __builtin_amdgcn_cvt_pkrtz(h2f0[2], h2f0[3]);
        nh2.p[2] = __builtin_amdgcn_cvt_pkrtz(h2f1[0], h2f1[1]);
        nh2.p[3] = __builtin_amdgcn_cvt_pkrtz(h2f1[2], h2f1[3]);

        h1B = nh1;
        h2B = nh2;
    }

    // ---- epilogue: publish h2(T-1) (f32, D layout) and apply FC ----
    CFENCE();
    #pragma unroll
    for (int M = 0; M < 2; ++M) {
        #pragma unroll
        for (int r = 0; r < 4; ++r) {
            const int j = 8 * hq + 4 * M + r;
            if (j < H_) ldsF[n][j] = (M == 0) ? h2f0[r] : h2f1[r];
        }
    }
    CFENCE();
    if (hq < DOUT) {
        float acc = fc_b[hq];
        #pragma unroll
        for (int j = 0; j < H_; ++j)
            acc = fmaf(ldsF[n][j], fc_w[hq * H_ + j], acc);
        out[samp * DOUT + hq] = acc;
    }
}

extern "C" void kernel_launch(void* const* d_in, const int* in_sizes, int n_in,
                              void* d_out, int out_size, void* d_ws, size_t ws_size,
                              hipStream_t stream) {
    (void)in_sizes; (void)n_in; (void)d_ws; (void)ws_size; (void)out_size;
    const float* x     = (const float*)d_in[0];
    const float* w_ih0 = (const float*)d_in[1];
    const float* w_hh0 = (const float*)d_in[2];
    const float* b_ih0 = (const float*)d_in[3];
    const float* b_hh0 = (const float*)d_in[4];
    const float* w_ih1 = (const float*)d_in[5];
    const float* w_hh1 = (const float*)d_in[6];
    const float* b_ih1 = (const float*)d_in[7];
    const float* b_hh1 = (const float*)d_in[8];
    const float* fc_w  = (const float*)d_in[9];
    const float* fc_b  = (const float*)d_in[10];
    float* out = (float*)d_out;

    hipLaunchKernelGGL(rnn_mfma, dim3(B_ / 16), dim3(64), 0, stream,
                       x, w_ih0, w_hh0, b_ih0, b_hh0,
                       w_ih1, w_hh1, b_ih1, b_hh1, fc_w, fc_b, out);
}